// Round 6
// baseline (146.618 us; speedup 1.0000x reference)
//
#include <hip/hip_runtime.h>
#include <hip/hip_bf16.h>

#define NN   8192
#define INF_ 256
#define OUTF 128
#define SLOPE 0.2f
#define NJC  4              // j-chunks (blocks splitting the j dimension)
#define JCHUNK (NN / NJC)   // 2048
#define NT   (JCHUNK / 128) // 16 tiles of 128 j

typedef float f32x4  __attribute__((ext_vector_type(4)));
typedef float f32x16 __attribute__((ext_vector_type(16)));
typedef short bf16x8 __attribute__((ext_vector_type(8)));
typedef int   i32x4  __attribute__((ext_vector_type(4)));
typedef unsigned short u16;
typedef u16 u16x4 __attribute__((ext_vector_type(4)));

__device__ __forceinline__ u16 f2bf(float f) {
  return __builtin_bit_cast(u16, __float2bfloat16(f));
}

// ---------------------------------------------------------------------------
// K0: compress adj (256 MB int32) -> bitmask bm (8 MB), pure streaming.
// bm layout matches K3's A-fragment read order:
//   byte for (row r, j-group jg = j>>3) at
//   ((r>>5)*64 + (jg>>4))*512 + (r&31)*16 + (jg&15)
//   i.e. [row-block 256][tile 64][row 32][16 bytes = 128 j-bits]
// Thread = one (r, jg): 32 B coalesced read, 1 B write (16-B segments/wave).
// ---------------------------------------------------------------------------
__global__ __launch_bounds__(256) void gat_k0(const int* __restrict__ adj,
                                              unsigned char* __restrict__ bm) {
  const int idx = blockIdx.x * 256 + threadIdx.x;
  const int r  = idx >> 10;
  const int jg = idx & 1023;
  const int* p = adj + (size_t)r * NN + jg * 8;
  i32x4 a0 = *(const i32x4*)p;
  i32x4 a1 = *(const i32x4*)(p + 4);
  unsigned b = 0;
#pragma unroll
  for (int e = 0; e < 4; e++) b |= (a0[e] > 0 ? 1u : 0u) << e;
#pragma unroll
  for (int e = 0; e < 4; e++) b |= (a1[e] > 0 ? 1u : 0u) << (e + 4);
  bm[(((size_t)(r >> 5) * 64 + (jg >> 4)) << 9) + ((r & 31) << 4) + (jg & 15)] =
      (unsigned char)b;
}

// ---------------------------------------------------------------------------
// K1: h = X @ W (fp32). Writes hbF (bf16, MFMA-B-fragment order), s1, s2.
// ---------------------------------------------------------------------------
__global__ __launch_bounds__(256) void gat_k1(
    const float* __restrict__ X, const float* __restrict__ W,
    const float* __restrict__ a, u16* __restrict__ hbF,
    float* __restrict__ s1, float* __restrict__ s2) {
  __shared__ float xs[32 * INF_];
  const int t = threadIdx.x;
  const int r0 = blockIdx.x * 32;
  {
    const f32x4* src = (const f32x4*)(X + (size_t)r0 * INF_);
    f32x4* dst = (f32x4*)xs;
    for (int i = t; i < 32 * INF_ / 4; i += 256) dst[i] = src[i];
  }
  __syncthreads();
  const int cg = t & 31;
  const int rg = t >> 5;
  float acc[4][4];
#pragma unroll
  for (int i = 0; i < 4; i++)
#pragma unroll
    for (int j = 0; j < 4; j++) acc[i][j] = 0.f;

  for (int k = 0; k < INF_; k += 4) {
    f32x4 xv[4];
#pragma unroll
    for (int i = 0; i < 4; i++) xv[i] = *(const f32x4*)&xs[(rg * 4 + i) * INF_ + k];
#pragma unroll
    for (int kk = 0; kk < 4; kk++) {
      f32x4 wv = *(const f32x4*)&W[(k + kk) * OUTF + cg * 4];
#pragma unroll
      for (int i = 0; i < 4; i++)
#pragma unroll
        for (int j = 0; j < 4; j++) acc[i][j] = fmaf(xv[i][kk], wv[j], acc[i][j]);
    }
  }

  f32x4 a1v = *(const f32x4*)&a[cg * 4];
  f32x4 a2v = *(const f32x4*)&a[OUTF + cg * 4];
  float p1[4], p2[4];
#pragma unroll
  for (int i = 0; i < 4; i++) {
    p1[i] = acc[i][0] * a1v[0] + acc[i][1] * a1v[1] + acc[i][2] * a1v[2] + acc[i][3] * a1v[3];
    p2[i] = acc[i][0] * a2v[0] + acc[i][1] * a2v[1] + acc[i][2] * a2v[2] + acc[i][3] * a2v[3];
  }
#pragma unroll
  for (int m = 1; m < 32; m <<= 1) {
#pragma unroll
    for (int i = 0; i < 4; i++) {
      p1[i] += __shfl_xor(p1[i], m);
      p2[i] += __shfl_xor(p2[i], m);
    }
  }
  if (cg == 0) {
#pragma unroll
    for (int i = 0; i < 4; i++) {
      s1[r0 + rg * 4 + i] = p1[i];
      s2[r0 + rg * 4 + i] = p2[i];
    }
  }

  const int R0 = r0 + rg * 4;
  const int J  = R0 >> 4;
  const int gg = (R0 >> 3) & 1;
  const int e0 = R0 & 7;
#pragma unroll
  for (int j = 0; j < 4; j++) {
    const int C = cg * 4 + j;
    u16x4 pk;
#pragma unroll
    for (int i = 0; i < 4; i++) pk[i] = f2bf(acc[i][j]);
    size_t flat = ((size_t)(J * 4 + (C >> 5)) * 64 + (C & 31) + 32 * gg) * 8 + e0;
    *(u16x4*)(hbF + flat) = pk;
  }
}

// ---------------------------------------------------------------------------
// K2: s2max = max(s2)
// ---------------------------------------------------------------------------
__global__ __launch_bounds__(256) void gat_k2(const float* __restrict__ s2,
                                              float* __restrict__ s2m) {
  __shared__ float sm[4];
  const int t = threadIdx.x;
  float m = -1e30f;
  for (int i = t; i < NN; i += 256) m = fmaxf(m, s2[i]);
#pragma unroll
  for (int k = 1; k < 64; k <<= 1) m = fmaxf(m, __shfl_xor(m, k));
  if ((t & 63) == 0) sm[t >> 6] = m;
  __syncthreads();
  if (t == 0) *s2m = fmaxf(fmaxf(sm[0], sm[1]), fmaxf(sm[2], sm[3]));
}

// ---------------------------------------------------------------------------
// K3: fused mask+lrelu+exp+PV over a 32-row x 2048-j slice, reading the
// 8 MB bitmask (L2-resident) instead of adj: 1 byte per lane per tile.
// NO LDS / NO barriers in the main loop — waves run free; loads are
// L1/L2-cached (bm 8 MB, hbF 2 MB, s2 32 KB).
// Grid 1024 = 256 row-groups x 4 j-chunks; 512 threads (8 waves, 4 blk/CU).
// ---------------------------------------------------------------------------
__device__ __forceinline__ void st16(float* dst, const f32x16& A, int g) {
#pragma unroll
  for (int r = 0; r < 16; r++) {
    const int dr = (r & 3) + 8 * (r >> 2) + 4 * g;
    dst[dr * 128] = A[r];
  }
}
__device__ __forceinline__ void ad16(float* dst, const f32x16& A, int g) {
#pragma unroll
  for (int r = 0; r < 16; r++) {
    const int dr = (r & 3) + 8 * (r >> 2) + 4 * g;
    dst[dr * 128] += A[r];
  }
}

__global__ __launch_bounds__(512, 4) void gat_k3(
    const unsigned char* __restrict__ bm, const u16* __restrict__ hbF,
    const float* __restrict__ s1g, const float* __restrict__ s2g,
    const float* __restrict__ s2maxp, float* __restrict__ part,
    float* __restrict__ dpart) {
  __shared__ float lred[8192];   // 32 KB, epilogue only
  __shared__ float dred[256];
  const int t = threadIdx.x;
  const int w = t >> 6;
  const int l = t & 63;
  const int rb = blockIdx.x & 255;
  const int jc = blockIdx.x >> 8;
  const int r0 = rb * 32;
  const int j0 = jc * JCHUNK;
  const int row = l & 31;
  const int g = l >> 5;

  const float s1r = s1g[r0 + row];
  const float s2m = *s2maxp;
  float Mi = s1r + s2m;
  Mi = fmaxf(Mi, SLOPE * Mi);       // lrelu of upper bound >= all row scores
  const float ar = s1r - Mi;        // lrelu(x)-Mi = max(ar+s2, br+SLOPE*s2)
  const float br = SLOPE * s1r - Mi;

  f32x16 acc0 = 0.f, acc1 = 0.f, acc2 = 0.f, acc3 = 0.f;

  const int c0 = 16 * w + 8 * g;    // this lane's j-offset within a tile
  // bitmask byte for (row, tile tt of this chunk, bits c0..c0+7):
  const unsigned char* bmp =
      bm + (((size_t)rb * 64 + jc * 16) << 9) + (row << 4) + (c0 >> 3);
  const float* sp = s2g + j0 + c0;
  const bf16x8* bp = (const bf16x8*)hbF + ((size_t)(jc * 128 + w) * 4) * 64 + l;

  float dsum = 0.f;
#pragma unroll 2
  for (int tt = 0; tt < NT; tt++) {
    const unsigned b = bmp[(size_t)tt << 9];
    const bf16x8* bq = bp + (size_t)tt * 2048;
    bf16x8 b0 = bq[0], b1 = bq[64], b2 = bq[128], b3 = bq[192];
    f32x4 s0  = *(const f32x4*)(sp + 128 * tt);
    f32x4 s1v = *(const f32x4*)(sp + 128 * tt + 4);

    bf16x8 af;
#pragma unroll
    for (int e = 0; e < 8; e++) {
      const float sv = (e < 4) ? s0[e] : s1v[e - 4];
      const float y = fmaxf(ar + sv, fmaf(SLOPE, sv, br));  // lrelu - Mi <= 0
      float p = __expf(y);
      p = ((b >> e) & 1u) ? p : 0.f;
      dsum += p;
      af[e] = (short)f2bf(p);
    }
    acc0 = __builtin_amdgcn_mfma_f32_32x32x16_bf16(af, b0, acc0, 0, 0, 0);
    acc1 = __builtin_amdgcn_mfma_f32_32x32x16_bf16(af, b1, acc1, 0, 0, 0);
    acc2 = __builtin_amdgcn_mfma_f32_32x32x16_bf16(af, b2, acc2, 0, 0, 0);
    acc3 = __builtin_amdgcn_mfma_f32_32x32x16_bf16(af, b3, acc3, 0, 0, 0);
  }

  // ---- denominator partial ----
  dsum += __shfl_xor(dsum, 32);
  if (l < 32) dred[w * 32 + l] = dsum;

  // ---- accumulator reduce across 8 waves into 2 LDS bufs (4 rounds) ----
  const int colw = l & 31;
  if (w < 2) {
    st16(&lred[w * 4096 + 0 * 32 + colw], acc0, g);
    st16(&lred[w * 4096 + 1 * 32 + colw], acc1, g);
    st16(&lred[w * 4096 + 2 * 32 + colw], acc2, g);
    st16(&lred[w * 4096 + 3 * 32 + colw], acc3, g);
  }
  __syncthreads();
  if (t < 32) {
    float d = 0.f;
#pragma unroll
    for (int w8 = 0; w8 < 8; w8++) d += dred[w8 * 32 + t];
    dpart[jc * NN + r0 + t] = d;
  }
  if (w == 2 || w == 3) {
    ad16(&lred[(w - 2) * 4096 + 0 * 32 + colw], acc0, g);
    ad16(&lred[(w - 2) * 4096 + 1 * 32 + colw], acc1, g);
    ad16(&lred[(w - 2) * 4096 + 2 * 32 + colw], acc2, g);
    ad16(&lred[(w - 2) * 4096 + 3 * 32 + colw], acc3, g);
  }
  __syncthreads();
  if (w == 4 || w == 5) {
    ad16(&lred[(w - 4) * 4096 + 0 * 32 + colw], acc0, g);
    ad16(&lred[(w - 4) * 4096 + 1 * 32 + colw], acc1, g);
    ad16(&lred[(w - 4) * 4096 + 2 * 32 + colw], acc2, g);
    ad16(&lred[(w - 4) * 4096 + 3 * 32 + colw], acc3, g);
  }
  __syncthreads();
  if (w == 6 || w == 7) {
    ad16(&lred[(w - 6) * 4096 + 0 * 32 + colw], acc0, g);
    ad16(&lred[(w - 6) * 4096 + 1 * 32 + colw], acc1, g);
    ad16(&lred[(w - 6) * 4096 + 2 * 32 + colw], acc2, g);
    ad16(&lred[(w - 6) * 4096 + 3 * 32 + colw], acc3, g);
  }
  __syncthreads();

  // ---- write fp32 partial: sum the 2 bufs ----
  const int flat = t * 8;  // row = t>>4, col = (t&15)*8
  f32x4 pa = *(f32x4*)&lred[flat];
  f32x4 pb = *(f32x4*)&lred[flat + 4];
  pa += *(f32x4*)&lred[4096 + flat];
  pb += *(f32x4*)&lred[4096 + flat + 4];
  float* pp = part + (size_t)jc * (NN * OUTF) + (size_t)r0 * OUTF + flat;
  *(f32x4*)pp = pa;
  *(f32x4*)(pp + 4) = pb;
}

// ---------------------------------------------------------------------------
// K4: combine 4 partials, divide by denom, elu, store.
// ---------------------------------------------------------------------------
__global__ __launch_bounds__(256) void gat_k4(
    const float* __restrict__ part, const float* __restrict__ dpart,
    float* __restrict__ out) {
  const int idx = blockIdx.x * 256 + threadIdx.x;
  const int e4 = idx * 4;
  const int i = e4 >> 7;
  f32x4 p = {0.f, 0.f, 0.f, 0.f};
  float d = 0.f;
#pragma unroll
  for (int jc = 0; jc < NJC; jc++) {
    p += *(const f32x4*)&part[(size_t)jc * (NN * OUTF) + e4];
    d += dpart[jc * NN + i];
  }
  d = fmaxf(d, 1e-30f);
  f32x4 r;
#pragma unroll
  for (int k = 0; k < 4; k++) {
    float v = p[k] / d;
    r[k] = (v > 0.f) ? v : expm1f(v);
  }
  *(f32x4*)&out[e4] = r;
}

extern "C" void kernel_launch(void* const* d_in, const int* in_sizes, int n_in,
                              void* d_out, int out_size, void* d_ws, size_t ws_size,
                              hipStream_t stream) {
  (void)in_sizes; (void)n_in; (void)out_size; (void)ws_size;
  const float* X  = (const float*)d_in[0];
  const int*  adj = (const int*)d_in[1];
  const float* W  = (const float*)d_in[2];
  const float* a  = (const float*)d_in[3];
  float* out = (float*)d_out;

  char* ws = (char*)d_ws;
  u16*   hbF   = (u16*)ws;                                  // 2 MB @ 0
  float* s1    = (float*)(ws + (2u << 20));                 // 32 KB
  float* s2    = (float*)(ws + (2u << 20) + (32u << 10));   // 32 KB
  float* s2m   = (float*)(ws + (2u << 20) + (64u << 10));   // 4 B
  float* dpart = (float*)(ws + (2u << 20) + (128u << 10));  // 128 KB
  unsigned char* bm = (unsigned char*)(ws + (3u << 20));    // 8 MB @ 3M
  float* part  = (float*)(ws + (12u << 20));                // 16 MB @ 12M

  gat_k0<<<NN * 1024 / 256, 256, 0, stream>>>(adj, bm);
  gat_k1<<<NN / 32, 256, 0, stream>>>(X, W, a, hbF, s1, s2);
  gat_k2<<<1, 256, 0, stream>>>(s2, s2m);
  gat_k3<<<256 * NJC, 512, 0, stream>>>(bm, hbF, s1, s2, s2m, part, dpart);
  gat_k4<<<(NN * OUTF / 4) / 256, 256, 0, stream>>>(part, dpart, out);
}

// Round 7
// 120.007 us; speedup vs baseline: 1.2217x; 1.2217x over previous
//
#include <hip/hip_runtime.h>
#include <hip/hip_bf16.h>

#define NN   8192
#define INF_ 256
#define OUTF 128
#define SLOPE 0.2f
#define NJC  4              // j-chunks (blocks splitting the j dimension)
#define JCHUNK (NN / NJC)   // 2048
#define NT   (JCHUNK / 128) // 16 tiles of 128 j

typedef float f32x4  __attribute__((ext_vector_type(4)));
typedef float f32x16 __attribute__((ext_vector_type(16)));
typedef short bf16x8 __attribute__((ext_vector_type(8)));
typedef int   i32x4  __attribute__((ext_vector_type(4)));
typedef unsigned short u16;
typedef u16 u16x4 __attribute__((ext_vector_type(4)));

__device__ __forceinline__ u16 f2bf(float f) {
  return __builtin_bit_cast(u16, __float2bfloat16(f));
}

// j <-> (jc, tt, w, g, e) mapping used by K1 (hbF layout), K3 (mask/s2/PV):
//   jc = j>>11; jg = (j&2047)>>3; e = j&7
//   tt = jg & 15  (tile index)    pr = jg>>4 (0..15): w = pr>>1, g = pr&1
// So lane (w,g) owns the 16-jg window (2w+g)*16 .. +15 of each chunk, and
// one 16-byte bm row-segment = that lane's mask bytes for ALL 16 tiles.

// ---------------------------------------------------------------------------
// K0: adj (256 MB) -> bm[r][jg] bitmask (8 MB), plain row-major, pure stream.
// Fully coalesced: 32 B read / 1 B write per thread (full-line wave writes).
// ---------------------------------------------------------------------------
__global__ __launch_bounds__(256) void gat_k0(const int* __restrict__ adj,
                                              unsigned char* __restrict__ bm) {
  const int idx = blockIdx.x * 256 + threadIdx.x;
  const int r  = idx >> 10;
  const int jg = idx & 1023;
  const int* p = adj + (size_t)r * NN + jg * 8;
  i32x4 a0 = *(const i32x4*)p;
  i32x4 a1 = *(const i32x4*)(p + 4);
  unsigned b = 0;
#pragma unroll
  for (int e = 0; e < 4; e++) b |= (a0[e] > 0 ? 1u : 0u) << e;
#pragma unroll
  for (int e = 0; e < 4; e++) b |= (a1[e] > 0 ? 1u : 0u) << (e + 4);
  bm[(size_t)r * 1024 + jg] = (unsigned char)b;
}

// ---------------------------------------------------------------------------
// K1: h = X @ W (fp32). Writes hbF (bf16, MFMA-B-fragment order with the
// permuted j->n mapping above), s1, s2.
// ---------------------------------------------------------------------------
__global__ __launch_bounds__(256) void gat_k1(
    const float* __restrict__ X, const float* __restrict__ W,
    const float* __restrict__ a, u16* __restrict__ hbF,
    float* __restrict__ s1, float* __restrict__ s2) {
  __shared__ float xs[32 * INF_];
  const int t = threadIdx.x;
  const int r0 = blockIdx.x * 32;
  {
    const f32x4* src = (const f32x4*)(X + (size_t)r0 * INF_);
    f32x4* dst = (f32x4*)xs;
    for (int i = t; i < 32 * INF_ / 4; i += 256) dst[i] = src[i];
  }
  __syncthreads();
  const int cg = t & 31;
  const int rg = t >> 5;
  float acc[4][4];
#pragma unroll
  for (int i = 0; i < 4; i++)
#pragma unroll
    for (int j = 0; j < 4; j++) acc[i][j] = 0.f;

  for (int k = 0; k < INF_; k += 4) {
    f32x4 xv[4];
#pragma unroll
    for (int i = 0; i < 4; i++) xv[i] = *(const f32x4*)&xs[(rg * 4 + i) * INF_ + k];
#pragma unroll
    for (int kk = 0; kk < 4; kk++) {
      f32x4 wv = *(const f32x4*)&W[(k + kk) * OUTF + cg * 4];
#pragma unroll
      for (int i = 0; i < 4; i++)
#pragma unroll
        for (int j = 0; j < 4; j++) acc[i][j] = fmaf(xv[i][kk], wv[j], acc[i][j]);
    }
  }

  f32x4 a1v = *(const f32x4*)&a[cg * 4];
  f32x4 a2v = *(const f32x4*)&a[OUTF + cg * 4];
  float p1[4], p2[4];
#pragma unroll
  for (int i = 0; i < 4; i++) {
    p1[i] = acc[i][0] * a1v[0] + acc[i][1] * a1v[1] + acc[i][2] * a1v[2] + acc[i][3] * a1v[3];
    p2[i] = acc[i][0] * a2v[0] + acc[i][1] * a2v[1] + acc[i][2] * a2v[2] + acc[i][3] * a2v[3];
  }
#pragma unroll
  for (int m = 1; m < 32; m <<= 1) {
#pragma unroll
    for (int i = 0; i < 4; i++) {
      p1[i] += __shfl_xor(p1[i], m);
      p2[i] += __shfl_xor(p2[i], m);
    }
  }
  if (cg == 0) {
#pragma unroll
    for (int i = 0; i < 4; i++) {
      s1[r0 + rg * 4 + i] = p1[i];
      s2[r0 + rg * 4 + i] = p2[i];
    }
  }

  // hbF scatter with the permuted mapping. R0 is 4-aligned so all 4 rows
  // share (jg, tt, w, g); e = e0..e0+3 -> one 8-byte store per col.
  const int R0 = r0 + rg * 4;
  const int jg = (R0 & 2047) >> 3;
  const int tt = jg & 15;
  const int pr = jg >> 4;
  const int wq = pr >> 1;
  const int gg = pr & 1;
  const int e0 = R0 & 7;
  const int n  = ((R0 >> 11) * 16 + tt) * 8 + wq;
#pragma unroll
  for (int j = 0; j < 4; j++) {
    const int C = cg * 4 + j;
    u16x4 pk;
#pragma unroll
    for (int i = 0; i < 4; i++) pk[i] = f2bf(acc[i][j]);
    size_t flat = ((size_t)(n * 4 + (C >> 5)) * 64 + (C & 31) + 32 * gg) * 8 + e0;
    *(u16x4*)(hbF + flat) = pk;
  }
}

// ---------------------------------------------------------------------------
// K2: s2max = max(s2)
// ---------------------------------------------------------------------------
__global__ __launch_bounds__(256) void gat_k2(const float* __restrict__ s2,
                                              float* __restrict__ s2m) {
  __shared__ float sm[4];
  const int t = threadIdx.x;
  float m = -1e30f;
  for (int i = t; i < NN; i += 256) m = fmaxf(m, s2[i]);
#pragma unroll
  for (int k = 1; k < 64; k <<= 1) m = fmaxf(m, __shfl_xor(m, k));
  if ((t & 63) == 0) sm[t >> 6] = m;
  __syncthreads();
  if (t == 0) *s2m = fmaxf(fmaxf(sm[0], sm[1]), fmaxf(sm[2], sm[3]));
}

// ---------------------------------------------------------------------------
// K3: fused mask+lrelu+exp+PV over a 32-row x 2048-j slice.
// Mask bits PRELOADED: one dwordx4 of bm per lane covers all 16 tiles.
// Main loop = hbF (2 MB, L2) + s2 (32 KB, L1) + VALU + MFMA. No LDS, no
// barriers, no per-tile dependent global loads.
// Grid 1024 = 256 row-groups x 4 j-chunks; 512 threads (8 waves).
// ---------------------------------------------------------------------------
__device__ __forceinline__ void st16(float* dst, const f32x16& A, int g) {
#pragma unroll
  for (int r = 0; r < 16; r++) {
    const int dr = (r & 3) + 8 * (r >> 2) + 4 * g;
    dst[dr * 128] = A[r];
  }
}
__device__ __forceinline__ void ad16(float* dst, const f32x16& A, int g) {
#pragma unroll
  for (int r = 0; r < 16; r++) {
    const int dr = (r & 3) + 8 * (r >> 2) + 4 * g;
    dst[dr * 128] += A[r];
  }
}

__global__ __launch_bounds__(512, 2) void gat_k3(
    const unsigned char* __restrict__ bm, const u16* __restrict__ hbF,
    const float* __restrict__ s1g, const float* __restrict__ s2g,
    const float* __restrict__ s2maxp, float* __restrict__ part,
    float* __restrict__ dpart) {
  __shared__ float lred[8192];   // 32 KB, epilogue only
  __shared__ float dred[256];
  const int t = threadIdx.x;
  const int w = t >> 6;
  const int l = t & 63;
  const int rb = blockIdx.x & 255;
  const int jc = blockIdx.x >> 8;
  const int r0 = rb * 32;
  const int row = l & 31;
  const int g = l >> 5;

  const float s1r = s1g[r0 + row];
  const float s2m = *s2maxp;
  float Mi = s1r + s2m;
  Mi = fmaxf(Mi, SLOPE * Mi);       // lrelu of upper bound >= all row scores
  const float ar = s1r - Mi;        // lrelu(x)-Mi = max(ar+s2, br+SLOPE*s2)
  const float br = SLOPE * s1r - Mi;

  // ---- mask preload: 16 bytes = this lane's bits for all 16 tiles ----
  const int pr = 2 * w + g;         // 0..15: this lane's 16-jg window
  const i32x4 bmv = *(const i32x4*)(bm + (size_t)(r0 + row) * 1024 +
                                    jc * 256 + pr * 16);

  f32x16 acc0 = 0.f, acc1 = 0.f, acc2 = 0.f, acc3 = 0.f;

  // s2 for this lane's j's: 8 consecutive floats per tile at window base
  const float* sp = s2g + jc * JCHUNK + pr * 128;
  const bf16x8* bp = (const bf16x8*)hbF + ((size_t)(jc * 128 + w) * 4) * 64 + l;

  float dsum = 0.f;
#pragma unroll
  for (int q4 = 0; q4 < 4; q4++) {
    const unsigned word = (unsigned)bmv[q4];
#pragma unroll
    for (int ti = 0; ti < 4; ti++) {
      const int tt = q4 * 4 + ti;
      const unsigned b = (word >> (ti * 8)) & 0xffu;
      const bf16x8* bq = bp + (size_t)tt * 2048;
      bf16x8 b0 = bq[0], b1 = bq[64], b2 = bq[128], b3 = bq[192];
      f32x4 s0  = *(const f32x4*)(sp + 8 * tt);
      f32x4 s1v = *(const f32x4*)(sp + 8 * tt + 4);

      bf16x8 af;
#pragma unroll
      for (int e = 0; e < 8; e++) {
        const float sv = (e < 4) ? s0[e] : s1v[e - 4];
        const float y = fmaxf(ar + sv, fmaf(SLOPE, sv, br));  // lrelu - Mi
        float p = __expf(y);
        p = ((b >> e) & 1u) ? p : 0.f;
        dsum += p;
        af[e] = (short)f2bf(p);
      }
      acc0 = __builtin_amdgcn_mfma_f32_32x32x16_bf16(af, b0, acc0, 0, 0, 0);
      acc1 = __builtin_amdgcn_mfma_f32_32x32x16_bf16(af, b1, acc1, 0, 0, 0);
      acc2 = __builtin_amdgcn_mfma_f32_32x32x16_bf16(af, b2, acc2, 0, 0, 0);
      acc3 = __builtin_amdgcn_mfma_f32_32x32x16_bf16(af, b3, acc3, 0, 0, 0);
    }
  }

  // ---- denominator partial ----
  dsum += __shfl_xor(dsum, 32);
  if (l < 32) dred[w * 32 + l] = dsum;

  // ---- accumulator reduce across 8 waves into 2 LDS bufs (4 rounds) ----
  const int colw = l & 31;
  if (w < 2) {
    st16(&lred[w * 4096 + 0 * 32 + colw], acc0, g);
    st16(&lred[w * 4096 + 1 * 32 + colw], acc1, g);
    st16(&lred[w * 4096 + 2 * 32 + colw], acc2, g);
    st16(&lred[w * 4096 + 3 * 32 + colw], acc3, g);
  }
  __syncthreads();
  if (t < 32) {
    float d = 0.f;
#pragma unroll
    for (int w8 = 0; w8 < 8; w8++) d += dred[w8 * 32 + t];
    dpart[jc * NN + r0 + t] = d;
  }
  if (w == 2 || w == 3) {
    ad16(&lred[(w - 2) * 4096 + 0 * 32 + colw], acc0, g);
    ad16(&lred[(w - 2) * 4096 + 1 * 32 + colw], acc1, g);
    ad16(&lred[(w - 2) * 4096 + 2 * 32 + colw], acc2, g);
    ad16(&lred[(w - 2) * 4096 + 3 * 32 + colw], acc3, g);
  }
  __syncthreads();
  if (w == 4 || w == 5) {
    ad16(&lred[(w - 4) * 4096 + 0 * 32 + colw], acc0, g);
    ad16(&lred[(w - 4) * 4096 + 1 * 32 + colw], acc1, g);
    ad16(&lred[(w - 4) * 4096 + 2 * 32 + colw], acc2, g);
    ad16(&lred[(w - 4) * 4096 + 3 * 32 + colw], acc3, g);
  }
  __syncthreads();
  if (w == 6 || w == 7) {
    ad16(&lred[(w - 6) * 4096 + 0 * 32 + colw], acc0, g);
    ad16(&lred[(w - 6) * 4096 + 1 * 32 + colw], acc1, g);
    ad16(&lred[(w - 6) * 4096 + 2 * 32 + colw], acc2, g);
    ad16(&lred[(w - 6) * 4096 + 3 * 32 + colw], acc3, g);
  }
  __syncthreads();

  // ---- write fp32 partial: sum the 2 bufs ----
  const int flat = t * 8;  // row = t>>4, col = (t&15)*8
  f32x4 pa = *(f32x4*)&lred[flat];
  f32x4 pb = *(f32x4*)&lred[flat + 4];
  pa += *(f32x4*)&lred[4096 + flat];
  pb += *(f32x4*)&lred[4096 + flat + 4];
  float* pp = part + (size_t)jc * (NN * OUTF) + (size_t)r0 * OUTF + flat;
  *(f32x4*)pp = pa;
  *(f32x4*)(pp + 4) = pb;
}

// ---------------------------------------------------------------------------
// K4: combine 4 partials, divide by denom, elu, store.
// ---------------------------------------------------------------------------
__global__ __launch_bounds__(256) void gat_k4(
    const float* __restrict__ part, const float* __restrict__ dpart,
    float* __restrict__ out) {
  const int idx = blockIdx.x * 256 + threadIdx.x;
  const int e4 = idx * 4;
  const int i = e4 >> 7;
  f32x4 p = {0.f, 0.f, 0.f, 0.f};
  float d = 0.f;
#pragma unroll
  for (int jc = 0; jc < NJC; jc++) {
    p += *(const f32x4*)&part[(size_t)jc * (NN * OUTF) + e4];
    d += dpart[jc * NN + i];
  }
  d = fmaxf(d, 1e-30f);
  f32x4 r;
#pragma unroll
  for (int k = 0; k < 4; k++) {
    float v = p[k] / d;
    r[k] = (v > 0.f) ? v : expm1f(v);
  }
  *(f32x4*)&out[e4] = r;
}

extern "C" void kernel_launch(void* const* d_in, const int* in_sizes, int n_in,
                              void* d_out, int out_size, void* d_ws, size_t ws_size,
                              hipStream_t stream) {
  (void)in_sizes; (void)n_in; (void)out_size; (void)ws_size;
  const float* X  = (const float*)d_in[0];
  const int*  adj = (const int*)d_in[1];
  const float* W  = (const float*)d_in[2];
  const float* a  = (const float*)d_in[3];
  float* out = (float*)d_out;

  char* ws = (char*)d_ws;
  u16*   hbF   = (u16*)ws;                                  // 2 MB @ 0
  float* s1    = (float*)(ws + (2u << 20));                 // 32 KB
  float* s2    = (float*)(ws + (2u << 20) + (32u << 10));   // 32 KB
  float* s2m   = (float*)(ws + (2u << 20) + (64u << 10));   // 4 B
  float* dpart = (float*)(ws + (2u << 20) + (128u << 10));  // 128 KB
  unsigned char* bm = (unsigned char*)(ws + (3u << 20));    // 8 MB @ 3M
  float* part  = (float*)(ws + (12u << 20));                // 16 MB @ 12M

  gat_k0<<<NN * 1024 / 256, 256, 0, stream>>>(adj, bm);
  gat_k1<<<NN / 32, 256, 0, stream>>>(X, W, a, hbF, s1, s2);
  gat_k2<<<1, 256, 0, stream>>>(s2, s2m);
  gat_k3<<<256 * NJC, 512, 0, stream>>>(bm, hbF, s1, s2, s2m, part, dpart);
  gat_k4<<<(NN * OUTF / 4) / 256, 256, 0, stream>>>(part, dpart, out);
}

// Round 8
// 114.056 us; speedup vs baseline: 1.2855x; 1.0522x over previous
//
#include <hip/hip_runtime.h>
#include <hip/hip_bf16.h>

#define NN   8192
#define INF_ 256
#define OUTF 128
#define SLOPE 0.2f
#define NJC  4              // j-chunks (blocks splitting the j dimension)
#define JCHUNK (NN / NJC)   // 2048
#define NT   (JCHUNK / 128) // 16 tiles of 128 j

typedef float f32x4  __attribute__((ext_vector_type(4)));
typedef float f32x16 __attribute__((ext_vector_type(16)));
typedef short bf16x8 __attribute__((ext_vector_type(8)));
typedef int   i32x4  __attribute__((ext_vector_type(4)));
typedef unsigned int u32;
typedef unsigned short u16;
typedef u16 u16x4 __attribute__((ext_vector_type(4)));

__device__ __forceinline__ u16 f2bf(float f) {
  return __builtin_bit_cast(u16, __float2bfloat16(f));
}

// j <-> (jc, tt, pr, e) mapping used by K1 (hbF layout) and K3 (mask/E/PV):
//   j = jc*2048 + pr*128 + tt*8 + e   (pr = 2w+g in K3)
// One 16-byte bm row-segment per lane = its mask bytes for ALL 16 tiles.

// ---------------------------------------------------------------------------
// K0: adj (256 MB) -> bm[r][jg] bitmask (8 MB), plain row-major, pure stream.
// ---------------------------------------------------------------------------
__global__ __launch_bounds__(256) void gat_k0(const int* __restrict__ adj,
                                              unsigned char* __restrict__ bm) {
  const int idx = blockIdx.x * 256 + threadIdx.x;
  const int r  = idx >> 10;
  const int jg = idx & 1023;
  const int* p = adj + (size_t)r * NN + jg * 8;
  i32x4 a0 = *(const i32x4*)p;
  i32x4 a1 = *(const i32x4*)(p + 4);
  unsigned b = 0;
#pragma unroll
  for (int e = 0; e < 4; e++) b |= (a0[e] > 0 ? 1u : 0u) << e;
#pragma unroll
  for (int e = 0; e < 4; e++) b |= (a1[e] > 0 ? 1u : 0u) << (e + 4);
  bm[(size_t)r * 1024 + jg] = (unsigned char)b;
}

// ---------------------------------------------------------------------------
// K1: h = X @ W (fp32). Writes hbF (bf16, MFMA-B-fragment order, permuted
// j->n mapping), s1, s2.
// ---------------------------------------------------------------------------
__global__ __launch_bounds__(256) void gat_k1(
    const float* __restrict__ X, const float* __restrict__ W,
    const float* __restrict__ a, u16* __restrict__ hbF,
    float* __restrict__ s1, float* __restrict__ s2) {
  __shared__ float xs[32 * INF_];
  const int t = threadIdx.x;
  const int r0 = blockIdx.x * 32;
  {
    const f32x4* src = (const f32x4*)(X + (size_t)r0 * INF_);
    f32x4* dst = (f32x4*)xs;
    for (int i = t; i < 32 * INF_ / 4; i += 256) dst[i] = src[i];
  }
  __syncthreads();
  const int cg = t & 31;
  const int rg = t >> 5;
  float acc[4][4];
#pragma unroll
  for (int i = 0; i < 4; i++)
#pragma unroll
    for (int j = 0; j < 4; j++) acc[i][j] = 0.f;

  for (int k = 0; k < INF_; k += 4) {
    f32x4 xv[4];
#pragma unroll
    for (int i = 0; i < 4; i++) xv[i] = *(const f32x4*)&xs[(rg * 4 + i) * INF_ + k];
#pragma unroll
    for (int kk = 0; kk < 4; kk++) {
      f32x4 wv = *(const f32x4*)&W[(k + kk) * OUTF + cg * 4];
#pragma unroll
      for (int i = 0; i < 4; i++)
#pragma unroll
        for (int j = 0; j < 4; j++) acc[i][j] = fmaf(xv[i][kk], wv[j], acc[i][j]);
    }
  }

  f32x4 a1v = *(const f32x4*)&a[cg * 4];
  f32x4 a2v = *(const f32x4*)&a[OUTF + cg * 4];
  float p1[4], p2[4];
#pragma unroll
  for (int i = 0; i < 4; i++) {
    p1[i] = acc[i][0] * a1v[0] + acc[i][1] * a1v[1] + acc[i][2] * a1v[2] + acc[i][3] * a1v[3];
    p2[i] = acc[i][0] * a2v[0] + acc[i][1] * a2v[1] + acc[i][2] * a2v[2] + acc[i][3] * a2v[3];
  }
#pragma unroll
  for (int m = 1; m < 32; m <<= 1) {
#pragma unroll
    for (int i = 0; i < 4; i++) {
      p1[i] += __shfl_xor(p1[i], m);
      p2[i] += __shfl_xor(p2[i], m);
    }
  }
  if (cg == 0) {
#pragma unroll
    for (int i = 0; i < 4; i++) {
      s1[r0 + rg * 4 + i] = p1[i];
      s2[r0 + rg * 4 + i] = p2[i];
    }
  }

  const int R0 = r0 + rg * 4;
  const int jg = (R0 & 2047) >> 3;
  const int tt = jg & 15;
  const int pr = jg >> 4;
  const int wq = pr >> 1;
  const int gg = pr & 1;
  const int e0 = R0 & 7;
  const int n  = ((R0 >> 11) * 16 + tt) * 8 + wq;
#pragma unroll
  for (int j = 0; j < 4; j++) {
    const int C = cg * 4 + j;
    u16x4 pk;
#pragma unroll
    for (int i = 0; i < 4; i++) pk[i] = f2bf(acc[i][j]);
    size_t flat = ((size_t)(n * 4 + (C >> 5)) * 64 + (C & 31) + 32 * gg) * 8 + e0;
    *(u16x4*)(hbF + flat) = pk;
  }
}

// ---------------------------------------------------------------------------
// K2: s2max = max(s2); E1 = exp(s2); E2 = exp(SLOPE*s2).
// ---------------------------------------------------------------------------
__global__ __launch_bounds__(1024) void gat_k2(const float* __restrict__ s2,
                                               float* __restrict__ s2m,
                                               float* __restrict__ E1,
                                               float* __restrict__ E2) {
  __shared__ float sm[16];
  const int t = threadIdx.x;
  float m = -1e30f;
  for (int i = t; i < NN / 4; i += 1024) {
    f32x4 v = ((const f32x4*)s2)[i];
    f32x4 e1, e2;
#pragma unroll
    for (int k = 0; k < 4; k++) {
      m = fmaxf(m, v[k]);
      e1[k] = __expf(v[k]);
      e2[k] = __expf(SLOPE * v[k]);
    }
    ((f32x4*)E1)[i] = e1;
    ((f32x4*)E2)[i] = e2;
  }
#pragma unroll
  for (int k = 1; k < 64; k <<= 1) m = fmaxf(m, __shfl_xor(m, k));
  if ((t & 63) == 0) sm[t >> 6] = m;
  __syncthreads();
  if (t == 0) {
    float mm = sm[0];
#pragma unroll
    for (int k = 1; k < 16; k++) mm = fmaxf(mm, sm[k]);
    *s2m = mm;
  }
}

// ---------------------------------------------------------------------------
// K3: fused mask+lrelu+softmax-numerator+PV over a 32-row x 2048-j slice.
// p = exp(lrelu(s1+s2)-Mi) = max(A*E1[j], B*E2[j]) by exp-monotonicity:
// no transcendentals in the loop. Mask bits preloaded (16 B/lane covers all
// 16 tiles). bf16 pack = biased add + v_perm. No LDS/barriers in main loop.
// launch_bounds(512,4): 128-VGPR cap -> 2 blocks/CU (16 waves).
// ---------------------------------------------------------------------------
__device__ __forceinline__ void st16(float* dst, const f32x16& A, int g) {
#pragma unroll
  for (int r = 0; r < 16; r++) {
    const int dr = (r & 3) + 8 * (r >> 2) + 4 * g;
    dst[dr * 128] = A[r];
  }
}
__device__ __forceinline__ void ad16(float* dst, const f32x16& A, int g) {
#pragma unroll
  for (int r = 0; r < 16; r++) {
    const int dr = (r & 3) + 8 * (r >> 2) + 4 * g;
    dst[dr * 128] += A[r];
  }
}

__global__ __launch_bounds__(512, 4) void gat_k3(
    const unsigned char* __restrict__ bm, const u16* __restrict__ hbF,
    const float* __restrict__ s1g, const float* __restrict__ E1,
    const float* __restrict__ E2, const float* __restrict__ s2maxp,
    float* __restrict__ part, float* __restrict__ dpart) {
  __shared__ float lred[8192];   // 32 KB, epilogue only
  __shared__ float dred[256];
  const int t = threadIdx.x;
  const int w = t >> 6;
  const int l = t & 63;
  const int rb = blockIdx.x & 255;
  const int jc = blockIdx.x >> 8;
  const int r0 = rb * 32;
  const int row = l & 31;
  const int g = l >> 5;

  const float s1r = s1g[r0 + row];
  const float s2m = *s2maxp;
  float Mi = s1r + s2m;
  Mi = fmaxf(Mi, SLOPE * Mi);           // lrelu of upper bound >= all scores
  const float A = __expf(s1r - Mi);     // p = max(A*E1[j], B*E2[j]) <= 1
  const float B = __expf(SLOPE * s1r - Mi);

  // ---- mask preload: 16 bytes = this lane's bits for all 16 tiles ----
  const int pr = 2 * w + g;             // 0..15: lane's 16-jg window
  const i32x4 bmv = *(const i32x4*)(bm + (size_t)(r0 + row) * 1024 +
                                    jc * 256 + pr * 16);

  f32x16 acc0 = 0.f, acc1 = 0.f, acc2 = 0.f, acc3 = 0.f;

  const float* e1p = E1 + jc * JCHUNK + pr * 128;
  const float* e2p = E2 + jc * JCHUNK + pr * 128;
  const bf16x8* bp = (const bf16x8*)hbF + ((size_t)(jc * 128 + w) * 4) * 64 + l;

  float dsA = 0.f, dsB = 0.f;
#pragma unroll
  for (int q4 = 0; q4 < 4; q4++) {
    const unsigned word = (unsigned)bmv[q4];
#pragma unroll
    for (int ti = 0; ti < 4; ti++) {
      const int tt = q4 * 4 + ti;
      const unsigned b = word >> (ti * 8);
      const bf16x8* bq = bp + (size_t)tt * 2048;
      bf16x8 b0 = bq[0], b1 = bq[64], b2 = bq[128], b3 = bq[192];
      f32x4 u0 = *(const f32x4*)(e1p + 8 * tt);
      f32x4 u1 = *(const f32x4*)(e1p + 8 * tt + 4);
      f32x4 v0 = *(const f32x4*)(e2p + 8 * tt);
      f32x4 v1 = *(const f32x4*)(e2p + 8 * tt + 4);
      const float uu[8] = {u0[0], u0[1], u0[2], u0[3], u1[0], u1[1], u1[2], u1[3]};
      const float vv[8] = {v0[0], v0[1], v0[2], v0[3], v1[0], v1[1], v1[2], v1[3]};

      u32 aw[4];
#pragma unroll
      for (int e = 0; e < 8; e += 2) {
        float pa = fmaxf(A * uu[e],     B * vv[e]);
        float pb = fmaxf(A * uu[e + 1], B * vv[e + 1]);
        pa = (b & (1u << e))       ? pa : 0.f;
        pb = (b & (1u << (e + 1))) ? pb : 0.f;
        dsA += pa;
        dsB += pb;
        aw[e >> 1] = __builtin_amdgcn_perm(
            __builtin_bit_cast(u32, pb) + 0x8000u,
            __builtin_bit_cast(u32, pa) + 0x8000u, 0x07060302u);
      }
      const bf16x8 af =
          __builtin_bit_cast(bf16x8, (i32x4){(int)aw[0], (int)aw[1],
                                             (int)aw[2], (int)aw[3]});
      acc0 = __builtin_amdgcn_mfma_f32_32x32x16_bf16(af, b0, acc0, 0, 0, 0);
      acc1 = __builtin_amdgcn_mfma_f32_32x32x16_bf16(af, b1, acc1, 0, 0, 0);
      acc2 = __builtin_amdgcn_mfma_f32_32x32x16_bf16(af, b2, acc2, 0, 0, 0);
      acc3 = __builtin_amdgcn_mfma_f32_32x32x16_bf16(af, b3, acc3, 0, 0, 0);
    }
  }
  float dsum = dsA + dsB;

  // ---- denominator partial ----
  dsum += __shfl_xor(dsum, 32);
  if (l < 32) dred[w * 32 + l] = dsum;

  // ---- accumulator reduce across 8 waves into 2 LDS bufs (4 rounds) ----
  const int colw = l & 31;
  if (w < 2) {
    st16(&lred[w * 4096 + 0 * 32 + colw], acc0, g);
    st16(&lred[w * 4096 + 1 * 32 + colw], acc1, g);
    st16(&lred[w * 4096 + 2 * 32 + colw], acc2, g);
    st16(&lred[w * 4096 + 3 * 32 + colw], acc3, g);
  }
  __syncthreads();
  if (t < 32) {
    float d = 0.f;
#pragma unroll
    for (int w8 = 0; w8 < 8; w8++) d += dred[w8 * 32 + t];
    dpart[jc * NN + r0 + t] = d;
  }
  if (w == 2 || w == 3) {
    ad16(&lred[(w - 2) * 4096 + 0 * 32 + colw], acc0, g);
    ad16(&lred[(w - 2) * 4096 + 1 * 32 + colw], acc1, g);
    ad16(&lred[(w - 2) * 4096 + 2 * 32 + colw], acc2, g);
    ad16(&lred[(w - 2) * 4096 + 3 * 32 + colw], acc3, g);
  }
  __syncthreads();
  if (w == 4 || w == 5) {
    ad16(&lred[(w - 4) * 4096 + 0 * 32 + colw], acc0, g);
    ad16(&lred[(w - 4) * 4096 + 1 * 32 + colw], acc1, g);
    ad16(&lred[(w - 4) * 4096 + 2 * 32 + colw], acc2, g);
    ad16(&lred[(w - 4) * 4096 + 3 * 32 + colw], acc3, g);
  }
  __syncthreads();
  if (w == 6 || w == 7) {
    ad16(&lred[(w - 6) * 4096 + 0 * 32 + colw], acc0, g);
    ad16(&lred[(w - 6) * 4096 + 1 * 32 + colw], acc1, g);
    ad16(&lred[(w - 6) * 4096 + 2 * 32 + colw], acc2, g);
    ad16(&lred[(w - 6) * 4096 + 3 * 32 + colw], acc3, g);
  }
  __syncthreads();

  // ---- write fp32 partial: sum the 2 bufs ----
  const int flat = t * 8;  // row = t>>4, col = (t&15)*8
  f32x4 pa = *(f32x4*)&lred[flat];
  f32x4 pb = *(f32x4*)&lred[flat + 4];
  pa += *(f32x4*)&lred[4096 + flat];
  pb += *(f32x4*)&lred[4096 + flat + 4];
  float* pp = part + (size_t)jc * (NN * OUTF) + (size_t)r0 * OUTF + flat;
  *(f32x4*)pp = pa;
  *(f32x4*)(pp + 4) = pb;
}

// ---------------------------------------------------------------------------
// K4: combine 4 partials, divide by denom, elu, store.
// ---------------------------------------------------------------------------
__global__ __launch_bounds__(256) void gat_k4(
    const float* __restrict__ part, const float* __restrict__ dpart,
    float* __restrict__ out) {
  const int idx = blockIdx.x * 256 + threadIdx.x;
  const int e4 = idx * 4;
  const int i = e4 >> 7;
  f32x4 p = {0.f, 0.f, 0.f, 0.f};
  float d = 0.f;
#pragma unroll
  for (int jc = 0; jc < NJC; jc++) {
    p += *(const f32x4*)&part[(size_t)jc * (NN * OUTF) + e4];
    d += dpart[jc * NN + i];
  }
  d = fmaxf(d, 1e-30f);
  f32x4 r;
#pragma unroll
  for (int k = 0; k < 4; k++) {
    float v = p[k] / d;
    r[k] = (v > 0.f) ? v : expm1f(v);
  }
  *(f32x4*)&out[e4] = r;
}

extern "C" void kernel_launch(void* const* d_in, const int* in_sizes, int n_in,
                              void* d_out, int out_size, void* d_ws, size_t ws_size,
                              hipStream_t stream) {
  (void)in_sizes; (void)n_in; (void)out_size; (void)ws_size;
  const float* X  = (const float*)d_in[0];
  const int*  adj = (const int*)d_in[1];
  const float* W  = (const float*)d_in[2];
  const float* a  = (const float*)d_in[3];
  float* out = (float*)d_out;

  char* ws = (char*)d_ws;
  u16*   hbF   = (u16*)ws;                                  // 2 MB @ 0
  float* s1    = (float*)(ws + (2u << 20));                 // 32 KB
  float* s2    = (float*)(ws + (2u << 20) + (32u << 10));   // 32 KB
  float* s2m   = (float*)(ws + (2u << 20) + (64u << 10));   // 4 B (pad 64K)
  float* E1    = (float*)(ws + (2u << 20) + (128u << 10));  // 32 KB
  float* E2    = (float*)(ws + (2u << 20) + (160u << 10));  // 32 KB
  float* dpart = (float*)(ws + (2u << 20) + (192u << 10));  // 128 KB
  unsigned char* bm = (unsigned char*)(ws + (3u << 20));    // 8 MB @ 3M
  float* part  = (float*)(ws + (12u << 20));                // 16 MB @ 12M

  gat_k0<<<NN * 1024 / 256, 256, 0, stream>>>(adj, bm);
  gat_k1<<<NN / 32, 256, 0, stream>>>(X, W, a, hbF, s1, s2);
  gat_k2<<<1, 1024, 0, stream>>>(s2, s2m, E1, E2);
  gat_k3<<<256 * NJC, 512, 0, stream>>>(bm, hbF, s1, E1, E2, s2m, part, dpart);
  gat_k4<<<(NN * OUTF / 4) / 256, 256, 0, stream>>>(part, dpart, out);
}

// Round 9
// 112.993 us; speedup vs baseline: 1.2976x; 1.0094x over previous
//
#include <hip/hip_runtime.h>
#include <hip/hip_bf16.h>

#define NN   8192
#define INF_ 256
#define OUTF 128
#define SLOPE 0.2f
#define NJC  4              // j-chunks (blocks splitting the j dimension)
#define JCHUNK (NN / NJC)   // 2048
#define NT   (JCHUNK / 128) // 16 tiles of 128 j

typedef float f32x4  __attribute__((ext_vector_type(4)));
typedef float f32x16 __attribute__((ext_vector_type(16)));
typedef short bf16x8 __attribute__((ext_vector_type(8)));
typedef int   i32x4  __attribute__((ext_vector_type(4)));
typedef unsigned int u32;
typedef unsigned short u16;
typedef u16 u16x4 __attribute__((ext_vector_type(4)));

__device__ __forceinline__ u16 f2bf(float f) {
  return __builtin_bit_cast(u16, __float2bfloat16(f));
}

// j <-> (jc, tt, pr, e) mapping used by K1 (hbF layout) and K3 (mask/E/PV):
//   j = jc*2048 + pr*128 + tt*8 + e   (pr = 2w+g in K3)

// ---------------------------------------------------------------------------
// K0: adj (256 MB) -> bm[r][jg] bitmask (8 MB), plain row-major, pure stream.
// ---------------------------------------------------------------------------
__global__ __launch_bounds__(256) void gat_k0(const int* __restrict__ adj,
                                              unsigned char* __restrict__ bm) {
  const int idx = blockIdx.x * 256 + threadIdx.x;
  const int r  = idx >> 10;
  const int jg = idx & 1023;
  const int* p = adj + (size_t)r * NN + jg * 8;
  i32x4 a0 = *(const i32x4*)p;
  i32x4 a1 = *(const i32x4*)(p + 4);
  unsigned b = 0;
#pragma unroll
  for (int e = 0; e < 4; e++) b |= (a0[e] > 0 ? 1u : 0u) << e;
#pragma unroll
  for (int e = 0; e < 4; e++) b |= (a1[e] > 0 ? 1u : 0u) << (e + 4);
  bm[(size_t)r * 1024 + jg] = (unsigned char)b;
}

// ---------------------------------------------------------------------------
// K1: h = X @ W (fp32). Writes hbF (bf16, MFMA-B-fragment order, permuted
// j->n mapping), s1, s2.
// ---------------------------------------------------------------------------
__global__ __launch_bounds__(256) void gat_k1(
    const float* __restrict__ X, const float* __restrict__ W,
    const float* __restrict__ a, u16* __restrict__ hbF,
    float* __restrict__ s1, float* __restrict__ s2) {
  __shared__ float xs[32 * INF_];
  const int t = threadIdx.x;
  const int r0 = blockIdx.x * 32;
  {
    const f32x4* src = (const f32x4*)(X + (size_t)r0 * INF_);
    f32x4* dst = (f32x4*)xs;
    for (int i = t; i < 32 * INF_ / 4; i += 256) dst[i] = src[i];
  }
  __syncthreads();
  const int cg = t & 31;
  const int rg = t >> 5;
  float acc[4][4];
#pragma unroll
  for (int i = 0; i < 4; i++)
#pragma unroll
    for (int j = 0; j < 4; j++) acc[i][j] = 0.f;

  for (int k = 0; k < INF_; k += 4) {
    f32x4 xv[4];
#pragma unroll
    for (int i = 0; i < 4; i++) xv[i] = *(const f32x4*)&xs[(rg * 4 + i) * INF_ + k];
#pragma unroll
    for (int kk = 0; kk < 4; kk++) {
      f32x4 wv = *(const f32x4*)&W[(k + kk) * OUTF + cg * 4];
#pragma unroll
      for (int i = 0; i < 4; i++)
#pragma unroll
        for (int j = 0; j < 4; j++) acc[i][j] = fmaf(xv[i][kk], wv[j], acc[i][j]);
    }
  }

  f32x4 a1v = *(const f32x4*)&a[cg * 4];
  f32x4 a2v = *(const f32x4*)&a[OUTF + cg * 4];
  float p1[4], p2[4];
#pragma unroll
  for (int i = 0; i < 4; i++) {
    p1[i] = acc[i][0] * a1v[0] + acc[i][1] * a1v[1] + acc[i][2] * a1v[2] + acc[i][3] * a1v[3];
    p2[i] = acc[i][0] * a2v[0] + acc[i][1] * a2v[1] + acc[i][2] * a2v[2] + acc[i][3] * a2v[3];
  }
#pragma unroll
  for (int m = 1; m < 32; m <<= 1) {
#pragma unroll
    for (int i = 0; i < 4; i++) {
      p1[i] += __shfl_xor(p1[i], m);
      p2[i] += __shfl_xor(p2[i], m);
    }
  }
  if (cg == 0) {
#pragma unroll
    for (int i = 0; i < 4; i++) {
      s1[r0 + rg * 4 + i] = p1[i];
      s2[r0 + rg * 4 + i] = p2[i];
    }
  }

  const int R0 = r0 + rg * 4;
  const int jg = (R0 & 2047) >> 3;
  const int tt = jg & 15;
  const int pr = jg >> 4;
  const int wq = pr >> 1;
  const int gg = pr & 1;
  const int e0 = R0 & 7;
  const int n  = ((R0 >> 11) * 16 + tt) * 8 + wq;
#pragma unroll
  for (int j = 0; j < 4; j++) {
    const int C = cg * 4 + j;
    u16x4 pk;
#pragma unroll
    for (int i = 0; i < 4; i++) pk[i] = f2bf(acc[i][j]);
    size_t flat = ((size_t)(n * 4 + (C >> 5)) * 64 + (C & 31) + 32 * gg) * 8 + e0;
    *(u16x4*)(hbF + flat) = pk;
  }
}

// ---------------------------------------------------------------------------
// K2: s2max = max(s2); E1 = exp(s2); E2 = exp(SLOPE*s2).
// ---------------------------------------------------------------------------
__global__ __launch_bounds__(1024) void gat_k2(const float* __restrict__ s2,
                                               float* __restrict__ s2m,
                                               float* __restrict__ E1,
                                               float* __restrict__ E2) {
  __shared__ float sm[16];
  const int t = threadIdx.x;
  float m = -1e30f;
  for (int i = t; i < NN / 4; i += 1024) {
    f32x4 v = ((const f32x4*)s2)[i];
    f32x4 e1, e2;
#pragma unroll
    for (int k = 0; k < 4; k++) {
      m = fmaxf(m, v[k]);
      e1[k] = __expf(v[k]);
      e2[k] = __expf(SLOPE * v[k]);
    }
    ((f32x4*)E1)[i] = e1;
    ((f32x4*)E2)[i] = e2;
  }
#pragma unroll
  for (int k = 1; k < 64; k <<= 1) m = fmaxf(m, __shfl_xor(m, k));
  if ((t & 63) == 0) sm[t >> 6] = m;
  __syncthreads();
  if (t == 0) {
    float mm = sm[0];
#pragma unroll
    for (int k = 1; k < 16; k++) mm = fmaxf(mm, sm[k]);
    *s2m = mm;
  }
}

// ---------------------------------------------------------------------------
// K3: fused mask+lrelu+softmax-numerator+PV over a 64-row x 2048-j slice.
// TWO row-groups per block share every B-fragment and E1/E2 load (2x
// arithmetic intensity per L2 byte; hbF traffic halves to 256 MB).
// p = max(A*E1[j], B*E2[j]); no transcendentals in the loop; masks
// preloaded (16 B/lane/group cover all 16 tiles). No LDS/barriers in
// main loop. launch_bounds(512,1): acc=128 VGPR, 1 block/CU.
// ---------------------------------------------------------------------------
__device__ __forceinline__ void st16(float* dst, const f32x16& A, int g) {
#pragma unroll
  for (int r = 0; r < 16; r++) {
    const int dr = (r & 3) + 8 * (r >> 2) + 4 * g;
    dst[dr * 128] = A[r];
  }
}
__device__ __forceinline__ void ad16(float* dst, const f32x16& A, int g) {
#pragma unroll
  for (int r = 0; r < 16; r++) {
    const int dr = (r & 3) + 8 * (r >> 2) + 4 * g;
    dst[dr * 128] += A[r];
  }
}

__global__ __launch_bounds__(512, 1) void gat_k3(
    const unsigned char* __restrict__ bm, const u16* __restrict__ hbF,
    const float* __restrict__ s1g, const float* __restrict__ E1,
    const float* __restrict__ E2, const float* __restrict__ s2maxp,
    float* __restrict__ part, float* __restrict__ dpart) {
  __shared__ float lred[8192];   // 32 KB, epilogue only
  __shared__ float dred[512];
  const int t = threadIdx.x;
  const int w = t >> 6;
  const int l = t & 63;
  const int rb = blockIdx.x & 127;
  const int jc = blockIdx.x >> 7;
  const int r0 = rb * 64;
  const int row = l & 31;
  const int g = l >> 5;

  const float s2m = *s2maxp;
  const float s1r0 = s1g[r0 + row];
  const float s1r1 = s1g[r0 + 32 + row];
  float Mi0 = s1r0 + s2m; Mi0 = fmaxf(Mi0, SLOPE * Mi0);
  float Mi1 = s1r1 + s2m; Mi1 = fmaxf(Mi1, SLOPE * Mi1);
  const float A0 = __expf(s1r0 - Mi0), B0 = __expf(SLOPE * s1r0 - Mi0);
  const float A1 = __expf(s1r1 - Mi1), B1 = __expf(SLOPE * s1r1 - Mi1);

  // ---- mask preload: 16 B per row-group = bits for all 16 tiles ----
  const int pr = 2 * w + g;             // 0..15: lane's 16-jg window
  const i32x4 bmv0 = *(const i32x4*)(bm + (size_t)(r0 + row) * 1024 +
                                     jc * 256 + pr * 16);
  const i32x4 bmv1 = *(const i32x4*)(bm + (size_t)(r0 + 32 + row) * 1024 +
                                     jc * 256 + pr * 16);

  f32x16 a00 = 0.f, a01 = 0.f, a02 = 0.f, a03 = 0.f;
  f32x16 a10 = 0.f, a11 = 0.f, a12 = 0.f, a13 = 0.f;

  const float* e1p = E1 + jc * JCHUNK + pr * 128;
  const float* e2p = E2 + jc * JCHUNK + pr * 128;
  const bf16x8* bp = (const bf16x8*)hbF + ((size_t)(jc * 128 + w) * 4) * 64 + l;

  float dsA0 = 0.f, dsB0 = 0.f, dsA1 = 0.f, dsB1 = 0.f;
#pragma unroll
  for (int q4 = 0; q4 < 4; q4++) {
    const unsigned w0 = (unsigned)bmv0[q4];
    const unsigned w1 = (unsigned)bmv1[q4];
#pragma unroll
    for (int ti = 0; ti < 4; ti++) {
      const int tt = q4 * 4 + ti;
      const unsigned b0m = w0 >> (ti * 8);
      const unsigned b1m = w1 >> (ti * 8);
      const bf16x8* bq = bp + (size_t)tt * 2048;
      bf16x8 b0 = bq[0], b1 = bq[64], b2 = bq[128], b3 = bq[192];
      f32x4 u0 = *(const f32x4*)(e1p + 8 * tt);
      f32x4 u1 = *(const f32x4*)(e1p + 8 * tt + 4);
      f32x4 v0 = *(const f32x4*)(e2p + 8 * tt);
      f32x4 v1 = *(const f32x4*)(e2p + 8 * tt + 4);
      const float uu[8] = {u0[0], u0[1], u0[2], u0[3], u1[0], u1[1], u1[2], u1[3]};
      const float vv[8] = {v0[0], v0[1], v0[2], v0[3], v1[0], v1[1], v1[2], v1[3]};

      u32 aw0[4], aw1[4];
#pragma unroll
      for (int e = 0; e < 8; e += 2) {
        float pa0 = fmaxf(A0 * uu[e],     B0 * vv[e]);
        float pb0 = fmaxf(A0 * uu[e + 1], B0 * vv[e + 1]);
        pa0 = (b0m & (1u << e))       ? pa0 : 0.f;
        pb0 = (b0m & (1u << (e + 1))) ? pb0 : 0.f;
        dsA0 += pa0; dsB0 += pb0;
        aw0[e >> 1] = __builtin_amdgcn_perm(
            __builtin_bit_cast(u32, pb0) + 0x8000u,
            __builtin_bit_cast(u32, pa0) + 0x8000u, 0x07060302u);
        float pa1 = fmaxf(A1 * uu[e],     B1 * vv[e]);
        float pb1 = fmaxf(A1 * uu[e + 1], B1 * vv[e + 1]);
        pa1 = (b1m & (1u << e))       ? pa1 : 0.f;
        pb1 = (b1m & (1u << (e + 1))) ? pb1 : 0.f;
        dsA1 += pa1; dsB1 += pb1;
        aw1[e >> 1] = __builtin_amdgcn_perm(
            __builtin_bit_cast(u32, pb1) + 0x8000u,
            __builtin_bit_cast(u32, pa1) + 0x8000u, 0x07060302u);
      }
      const bf16x8 af0 = __builtin_bit_cast(
          bf16x8, (i32x4){(int)aw0[0], (int)aw0[1], (int)aw0[2], (int)aw0[3]});
      const bf16x8 af1 = __builtin_bit_cast(
          bf16x8, (i32x4){(int)aw1[0], (int)aw1[1], (int)aw1[2], (int)aw1[3]});
      a00 = __builtin_amdgcn_mfma_f32_32x32x16_bf16(af0, b0, a00, 0, 0, 0);
      a10 = __builtin_amdgcn_mfma_f32_32x32x16_bf16(af1, b0, a10, 0, 0, 0);
      a01 = __builtin_amdgcn_mfma_f32_32x32x16_bf16(af0, b1, a01, 0, 0, 0);
      a11 = __builtin_amdgcn_mfma_f32_32x32x16_bf16(af1, b1, a11, 0, 0, 0);
      a02 = __builtin_amdgcn_mfma_f32_32x32x16_bf16(af0, b2, a02, 0, 0, 0);
      a12 = __builtin_amdgcn_mfma_f32_32x32x16_bf16(af1, b2, a12, 0, 0, 0);
      a03 = __builtin_amdgcn_mfma_f32_32x32x16_bf16(af0, b3, a03, 0, 0, 0);
      a13 = __builtin_amdgcn_mfma_f32_32x32x16_bf16(af1, b3, a13, 0, 0, 0);
    }
  }
  float dsum0 = dsA0 + dsB0;
  float dsum1 = dsA1 + dsB1;

  // ---- denominator partials (both row-groups) ----
  dsum0 += __shfl_xor(dsum0, 32);
  dsum1 += __shfl_xor(dsum1, 32);
  if (l < 32) {
    dred[w * 64 + l] = dsum0;
    dred[w * 64 + 32 + l] = dsum1;
  }

  const int colw = l & 31;
  const int flat = t * 8;  // row = t>>4, col = (t&15)*8

  // ======== pass 0: row-group 0 ========
  if (w < 2) {
    st16(&lred[w * 4096 + 0 * 32 + colw], a00, g);
    st16(&lred[w * 4096 + 1 * 32 + colw], a01, g);
    st16(&lred[w * 4096 + 2 * 32 + colw], a02, g);
    st16(&lred[w * 4096 + 3 * 32 + colw], a03, g);
  }
  __syncthreads();
  if (t < 64) {
    float d = 0.f;
#pragma unroll
    for (int w8 = 0; w8 < 8; w8++) d += dred[w8 * 64 + t];
    dpart[jc * NN + r0 + t] = d;
  }
  if (w == 2 || w == 3) {
    ad16(&lred[(w - 2) * 4096 + 0 * 32 + colw], a00, g);
    ad16(&lred[(w - 2) * 4096 + 1 * 32 + colw], a01, g);
    ad16(&lred[(w - 2) * 4096 + 2 * 32 + colw], a02, g);
    ad16(&lred[(w - 2) * 4096 + 3 * 32 + colw], a03, g);
  }
  __syncthreads();
  if (w == 4 || w == 5) {
    ad16(&lred[(w - 4) * 4096 + 0 * 32 + colw], a00, g);
    ad16(&lred[(w - 4) * 4096 + 1 * 32 + colw], a01, g);
    ad16(&lred[(w - 4) * 4096 + 2 * 32 + colw], a02, g);
    ad16(&lred[(w - 4) * 4096 + 3 * 32 + colw], a03, g);
  }
  __syncthreads();
  if (w == 6 || w == 7) {
    ad16(&lred[(w - 6) * 4096 + 0 * 32 + colw], a00, g);
    ad16(&lred[(w - 6) * 4096 + 1 * 32 + colw], a01, g);
    ad16(&lred[(w - 6) * 4096 + 2 * 32 + colw], a02, g);
    ad16(&lred[(w - 6) * 4096 + 3 * 32 + colw], a03, g);
  }
  __syncthreads();
  {
    f32x4 pa = *(f32x4*)&lred[flat];
    f32x4 pb = *(f32x4*)&lred[flat + 4];
    pa += *(f32x4*)&lred[4096 + flat];
    pb += *(f32x4*)&lred[4096 + flat + 4];
    float* pp = part + (size_t)jc * (NN * OUTF) + (size_t)r0 * OUTF + flat;
    *(f32x4*)pp = pa;
    *(f32x4*)(pp + 4) = pb;
  }
  __syncthreads();

  // ======== pass 1: row-group 1 ========
  if (w < 2) {
    st16(&lred[w * 4096 + 0 * 32 + colw], a10, g);
    st16(&lred[w * 4096 + 1 * 32 + colw], a11, g);
    st16(&lred[w * 4096 + 2 * 32 + colw], a12, g);
    st16(&lred[w * 4096 + 3 * 32 + colw], a13, g);
  }
  __syncthreads();
  if (w == 2 || w == 3) {
    ad16(&lred[(w - 2) * 4096 + 0 * 32 + colw], a10, g);
    ad16(&lred[(w - 2) * 4096 + 1 * 32 + colw], a11, g);
    ad16(&lred[(w - 2) * 4096 + 2 * 32 + colw], a12, g);
    ad16(&lred[(w - 2) * 4096 + 3 * 32 + colw], a13, g);
  }
  __syncthreads();
  if (w == 4 || w == 5) {
    ad16(&lred[(w - 4) * 4096 + 0 * 32 + colw], a10, g);
    ad16(&lred[(w - 4) * 4096 + 1 * 32 + colw], a11, g);
    ad16(&lred[(w - 4) * 4096 + 2 * 32 + colw], a12, g);
    ad16(&lred[(w - 4) * 4096 + 3 * 32 + colw], a13, g);
  }
  __syncthreads();
  if (w == 6 || w == 7) {
    ad16(&lred[(w - 6) * 4096 + 0 * 32 + colw], a10, g);
    ad16(&lred[(w - 6) * 4096 + 1 * 32 + colw], a11, g);
    ad16(&lred[(w - 6) * 4096 + 2 * 32 + colw], a12, g);
    ad16(&lred[(w - 6) * 4096 + 3 * 32 + colw], a13, g);
  }
  __syncthreads();
  {
    f32x4 pa = *(f32x4*)&lred[flat];
    f32x4 pb = *(f32x4*)&lred[flat + 4];
    pa += *(f32x4*)&lred[4096 + flat];
    pb += *(f32x4*)&lred[4096 + flat + 4];
    float* pp = part + (size_t)jc * (NN * OUTF) +
                (size_t)(r0 + 32) * OUTF + flat;
    *(f32x4*)pp = pa;
    *(f32x4*)(pp + 4) = pb;
  }
}

// ---------------------------------------------------------------------------
// K4: combine 4 partials, divide by denom, elu, store.
// ---------------------------------------------------------------------------
__global__ __launch_bounds__(256) void gat_k4(
    const float* __restrict__ part, const float* __restrict__ dpart,
    float* __restrict__ out) {
  const int idx = blockIdx.x * 256 + threadIdx.x;
  const int e4 = idx * 4;
  const int i = e4 >> 7;
  f32x4 p = {0.f, 0.f, 0.f, 0.f};
  float d = 0.f;
#pragma unroll
  for (int jc = 0; jc < NJC; jc++) {
    p += *(const f32x4*)&part[(size_t)jc * (NN * OUTF) + e4];
    d += dpart[jc * NN + i];
  }
  d = fmaxf(d, 1e-30f);
  f32x4 r;
#pragma unroll
  for (int k = 0; k < 4; k++) {
    float v = p[k] / d;
    r[k] = (v > 0.f) ? v : expm1f(v);
  }
  *(f32x4*)&out[e4] = r;
}

extern "C" void kernel_launch(void* const* d_in, const int* in_sizes, int n_in,
                              void* d_out, int out_size, void* d_ws, size_t ws_size,
                              hipStream_t stream) {
  (void)in_sizes; (void)n_in; (void)out_size; (void)ws_size;
  const float* X  = (const float*)d_in[0];
  const int*  adj = (const int*)d_in[1];
  const float* W  = (const float*)d_in[2];
  const float* a  = (const float*)d_in[3];
  float* out = (float*)d_out;

  char* ws = (char*)d_ws;
  u16*   hbF   = (u16*)ws;                                  // 2 MB @ 0
  float* s1    = (float*)(ws + (2u << 20));                 // 32 KB
  float* s2    = (float*)(ws + (2u << 20) + (32u << 10));   // 32 KB
  float* s2m   = (float*)(ws + (2u << 20) + (64u << 10));   // 4 B (pad 64K)
  float* E1    = (float*)(ws + (2u << 20) + (128u << 10));  // 32 KB
  float* E2    = (float*)(ws + (2u << 20) + (160u << 10));  // 32 KB
  float* dpart = (float*)(ws + (2u << 20) + (192u << 10));  // 128 KB
  unsigned char* bm = (unsigned char*)(ws + (3u << 20));    // 8 MB @ 3M
  float* part  = (float*)(ws + (12u << 20));                // 16 MB @ 12M

  gat_k0<<<NN * 1024 / 256, 256, 0, stream>>>(adj, bm);
  gat_k1<<<NN / 32, 256, 0, stream>>>(X, W, a, hbF, s1, s2);
  gat_k2<<<1, 1024, 0, stream>>>(s2, s2m, E1, E2);
  gat_k3<<<128 * NJC, 512, 0, stream>>>(bm, hbF, s1, E1, E2, s2m, part, dpart);
  gat_k4<<<(NN * OUTF / 4) / 256, 256, 0, stream>>>(part, dpart, out);
}

// Round 10
// 103.155 us; speedup vs baseline: 1.4213x; 1.0954x over previous
//
#include <hip/hip_runtime.h>
#include <hip/hip_bf16.h>

#define NN   8192
#define INF_ 256
#define OUTF 128
#define SLOPE 0.2f
#define NJC  4              // j-chunks (blocks splitting the j dimension)
#define JCHUNK (NN / NJC)   // 2048
#define NT   (JCHUNK / 128) // 16 tiles of 128 j

typedef float f32x4  __attribute__((ext_vector_type(4)));
typedef float f32x16 __attribute__((ext_vector_type(16)));
typedef short bf16x8 __attribute__((ext_vector_type(8)));
typedef int   i32x4  __attribute__((ext_vector_type(4)));
typedef unsigned int u32;
typedef unsigned short u16;
typedef u16 u16x4 __attribute__((ext_vector_type(4)));

__device__ __forceinline__ u16 f2bf(float f) {
  return __builtin_bit_cast(u16, __float2bfloat16(f));
}

// j <-> (jc, tt, pr, e) mapping used by K1 (hbF layout) and K3 (mask/E/PV):
//   j = jc*2048 + pr*128 + tt*8 + e   (pr = 2w+g in K3)

// ---------------------------------------------------------------------------
// K1: h = X @ W (fp32). Writes hbF (bf16, MFMA-B-fragment order, permuted
// j->n mapping), s1, s2.
// ---------------------------------------------------------------------------
__global__ __launch_bounds__(256) void gat_k1(
    const float* __restrict__ X, const float* __restrict__ W,
    const float* __restrict__ a, u16* __restrict__ hbF,
    float* __restrict__ s1, float* __restrict__ s2) {
  __shared__ float xs[32 * INF_];
  const int t = threadIdx.x;
  const int r0 = blockIdx.x * 32;
  {
    const f32x4* src = (const f32x4*)(X + (size_t)r0 * INF_);
    f32x4* dst = (f32x4*)xs;
    for (int i = t; i < 32 * INF_ / 4; i += 256) dst[i] = src[i];
  }
  __syncthreads();
  const int cg = t & 31;
  const int rg = t >> 5;
  float acc[4][4];
#pragma unroll
  for (int i = 0; i < 4; i++)
#pragma unroll
    for (int j = 0; j < 4; j++) acc[i][j] = 0.f;

  for (int k = 0; k < INF_; k += 4) {
    f32x4 xv[4];
#pragma unroll
    for (int i = 0; i < 4; i++) xv[i] = *(const f32x4*)&xs[(rg * 4 + i) * INF_ + k];
#pragma unroll
    for (int kk = 0; kk < 4; kk++) {
      f32x4 wv = *(const f32x4*)&W[(k + kk) * OUTF + cg * 4];
#pragma unroll
      for (int i = 0; i < 4; i++)
#pragma unroll
        for (int j = 0; j < 4; j++) acc[i][j] = fmaf(xv[i][kk], wv[j], acc[i][j]);
    }
  }

  f32x4 a1v = *(const f32x4*)&a[cg * 4];
  f32x4 a2v = *(const f32x4*)&a[OUTF + cg * 4];
  float p1[4], p2[4];
#pragma unroll
  for (int i = 0; i < 4; i++) {
    p1[i] = acc[i][0] * a1v[0] + acc[i][1] * a1v[1] + acc[i][2] * a1v[2] + acc[i][3] * a1v[3];
    p2[i] = acc[i][0] * a2v[0] + acc[i][1] * a2v[1] + acc[i][2] * a2v[2] + acc[i][3] * a2v[3];
  }
#pragma unroll
  for (int m = 1; m < 32; m <<= 1) {
#pragma unroll
    for (int i = 0; i < 4; i++) {
      p1[i] += __shfl_xor(p1[i], m);
      p2[i] += __shfl_xor(p2[i], m);
    }
  }
  if (cg == 0) {
#pragma unroll
    for (int i = 0; i < 4; i++) {
      s1[r0 + rg * 4 + i] = p1[i];
      s2[r0 + rg * 4 + i] = p2[i];
    }
  }

  const int R0 = r0 + rg * 4;
  const int jg = (R0 & 2047) >> 3;
  const int tt = jg & 15;
  const int pr = jg >> 4;
  const int wq = pr >> 1;
  const int gg = pr & 1;
  const int e0 = R0 & 7;
  const int n  = ((R0 >> 11) * 16 + tt) * 8 + wq;
#pragma unroll
  for (int j = 0; j < 4; j++) {
    const int C = cg * 4 + j;
    u16x4 pk;
#pragma unroll
    for (int i = 0; i < 4; i++) pk[i] = f2bf(acc[i][j]);
    size_t flat = ((size_t)(n * 4 + (C >> 5)) * 64 + (C & 31) + 32 * gg) * 8 + e0;
    *(u16x4*)(hbF + flat) = pk;
  }
}

// ---------------------------------------------------------------------------
// K2: E1 = exp(s2); E2 = exp(SLOPE*s2); bmax[block] = max(s2 chunk).
// 8 blocks x 256 threads (1 f32x4 each) - no single-CU serialization.
// ---------------------------------------------------------------------------
__global__ __launch_bounds__(256) void gat_k2(const float* __restrict__ s2,
                                              float* __restrict__ bmax,
                                              float* __restrict__ E1,
                                              float* __restrict__ E2) {
  __shared__ float sm[4];
  const int t = threadIdx.x;
  const int i = blockIdx.x * 256 + t;
  f32x4 v = ((const f32x4*)s2)[i];
  f32x4 e1, e2;
  float m = -1e30f;
#pragma unroll
  for (int k = 0; k < 4; k++) {
    m = fmaxf(m, v[k]);
    e1[k] = __expf(v[k]);
    e2[k] = __expf(SLOPE * v[k]);
  }
  ((f32x4*)E1)[i] = e1;
  ((f32x4*)E2)[i] = e2;
#pragma unroll
  for (int k = 1; k < 64; k <<= 1) m = fmaxf(m, __shfl_xor(m, k));
  if ((t & 63) == 0) sm[t >> 6] = m;
  __syncthreads();
  if (t == 0)
    bmax[blockIdx.x] = fmaxf(fmaxf(sm[0], sm[1]), fmaxf(sm[2], sm[3]));
}

// ---------------------------------------------------------------------------
// K3: FUSED adj-stream + mask + lrelu + softmax-numerator + PV over a
// 32-row x 2048-j slice.
//  phase 1: block streams its 32x2048 adj slab (256 KB) fully coalesced,
//           packs to an 8 KB LDS bitmask (bits[row][jg]).
//  phase 2: lanes preload their 16 mask bytes (reg), then R7-style loop:
//           p = max(A*E1[j], B*E2[j]), no transcendentals, hbF from L2.
// 2 blocks/CU (launch_bounds(512,4)): co-resident blocks overlap phase 1
// (HBM stream) with phase 2 (compute) - no serial compression pass.
// Grid 1024 = 256 row-groups x 4 j-chunks.
// ---------------------------------------------------------------------------
__device__ __forceinline__ void st16(float* dst, const f32x16& A, int g) {
#pragma unroll
  for (int r = 0; r < 16; r++) {
    const int dr = (r & 3) + 8 * (r >> 2) + 4 * g;
    dst[dr * 128] = A[r];
  }
}
__device__ __forceinline__ void ad16(float* dst, const f32x16& A, int g) {
#pragma unroll
  for (int r = 0; r < 16; r++) {
    const int dr = (r & 3) + 8 * (r >> 2) + 4 * g;
    dst[dr * 128] += A[r];
  }
}

__global__ __launch_bounds__(512, 4) void gat_k3(
    const int* __restrict__ adj, const u16* __restrict__ hbF,
    const float* __restrict__ s1g, const float* __restrict__ E1,
    const float* __restrict__ E2, const float* __restrict__ bmax,
    float* __restrict__ part, float* __restrict__ dpart) {
  __shared__ float lred[8192];   // 32 KB; bytes 0..8191 = phase-1 bitmask
  __shared__ float dred[256];
  const int t = threadIdx.x;
  const int w = t >> 6;
  const int l = t & 63;
  const int rb = blockIdx.x & 255;
  const int jc = blockIdx.x >> 8;
  const int r0 = rb * 32;
  const int row = l & 31;
  const int g = l >> 5;

  // ---- phase 1: adj slab -> LDS bitmask (coalesced 32 B per thread-chunk) --
  unsigned char* bits = (unsigned char*)lred;
  {
    const int prow = t >> 4;   // 0..31
    const int cl = t & 15;
    const int* ap = adj + (size_t)(r0 + prow) * NN + jc * JCHUNK + cl * 8;
#pragma unroll 4
    for (int k = 0; k < 16; k++) {
      i32x4 x0 = *(const i32x4*)(ap + k * 128);
      i32x4 x1 = *(const i32x4*)(ap + k * 128 + 4);
      unsigned b = 0;
#pragma unroll
      for (int e = 0; e < 4; e++) b |= (x0[e] > 0 ? 1u : 0u) << e;
#pragma unroll
      for (int e = 0; e < 4; e++) b |= (x1[e] > 0 ? 1u : 0u) << (e + 4);
      bits[prow * 256 + k * 16 + cl] = (unsigned char)b;
    }
  }
  __syncthreads();

  // ---- per-row constants ----
  float s2m = bmax[0];
#pragma unroll
  for (int k = 1; k < 8; k++) s2m = fmaxf(s2m, bmax[k]);
  const float s1r = s1g[r0 + row];
  float Mi = s1r + s2m;
  Mi = fmaxf(Mi, SLOPE * Mi);           // lrelu of upper bound >= all scores
  const float A = __expf(s1r - Mi);     // p = max(A*E1[j], B*E2[j]) <= 1
  const float B = __expf(SLOPE * s1r - Mi);

  // ---- mask preload from LDS: 16 bytes = bits for all 16 tiles ----
  const int pr = 2 * w + g;             // 0..15: lane's 16-jg window
  const i32x4 bmv = *(const i32x4*)(bits + row * 256 + pr * 16);
  __syncthreads();                      // lred reusable after this

  f32x16 acc0 = 0.f, acc1 = 0.f, acc2 = 0.f, acc3 = 0.f;

  const float* e1p = E1 + jc * JCHUNK + pr * 128;
  const float* e2p = E2 + jc * JCHUNK + pr * 128;
  const bf16x8* bp = (const bf16x8*)hbF + ((size_t)(jc * 128 + w) * 4) * 64 + l;

  float dsA = 0.f, dsB = 0.f;
#pragma unroll
  for (int q4 = 0; q4 < 4; q4++) {
    const unsigned word = (unsigned)bmv[q4];
#pragma unroll
    for (int ti = 0; ti < 4; ti++) {
      const int tt = q4 * 4 + ti;
      const unsigned b = word >> (ti * 8);
      const bf16x8* bq = bp + (size_t)tt * 2048;
      bf16x8 b0 = bq[0], b1 = bq[64], b2 = bq[128], b3 = bq[192];
      f32x4 u0 = *(const f32x4*)(e1p + 8 * tt);
      f32x4 u1 = *(const f32x4*)(e1p + 8 * tt + 4);
      f32x4 v0 = *(const f32x4*)(e2p + 8 * tt);
      f32x4 v1 = *(const f32x4*)(e2p + 8 * tt + 4);
      const float uu[8] = {u0[0], u0[1], u0[2], u0[3], u1[0], u1[1], u1[2], u1[3]};
      const float vv[8] = {v0[0], v0[1], v0[2], v0[3], v1[0], v1[1], v1[2], v1[3]};

      u32 aw[4];
#pragma unroll
      for (int e = 0; e < 8; e += 2) {
        float pa = fmaxf(A * uu[e],     B * vv[e]);
        float pb = fmaxf(A * uu[e + 1], B * vv[e + 1]);
        pa = (b & (1u << e))       ? pa : 0.f;
        pb = (b & (1u << (e + 1))) ? pb : 0.f;
        dsA += pa;
        dsB += pb;
        aw[e >> 1] = __builtin_amdgcn_perm(
            __builtin_bit_cast(u32, pb) + 0x8000u,
            __builtin_bit_cast(u32, pa) + 0x8000u, 0x07060302u);
      }
      const bf16x8 af =
          __builtin_bit_cast(bf16x8, (i32x4){(int)aw[0], (int)aw[1],
                                             (int)aw[2], (int)aw[3]});
      acc0 = __builtin_amdgcn_mfma_f32_32x32x16_bf16(af, b0, acc0, 0, 0, 0);
      acc1 = __builtin_amdgcn_mfma_f32_32x32x16_bf16(af, b1, acc1, 0, 0, 0);
      acc2 = __builtin_amdgcn_mfma_f32_32x32x16_bf16(af, b2, acc2, 0, 0, 0);
      acc3 = __builtin_amdgcn_mfma_f32_32x32x16_bf16(af, b3, acc3, 0, 0, 0);
    }
  }
  float dsum = dsA + dsB;

  // ---- denominator partial ----
  dsum += __shfl_xor(dsum, 32);
  if (l < 32) dred[w * 32 + l] = dsum;

  // ---- accumulator reduce across 8 waves into 2 LDS bufs (4 rounds) ----
  const int colw = l & 31;
  if (w < 2) {
    st16(&lred[w * 4096 + 0 * 32 + colw], acc0, g);
    st16(&lred[w * 4096 + 1 * 32 + colw], acc1, g);
    st16(&lred[w * 4096 + 2 * 32 + colw], acc2, g);
    st16(&lred[w * 4096 + 3 * 32 + colw], acc3, g);
  }
  __syncthreads();
  if (t < 32) {
    float d = 0.f;
#pragma unroll
    for (int w8 = 0; w8 < 8; w8++) d += dred[w8 * 32 + t];
    dpart[jc * NN + r0 + t] = d;
  }
  if (w == 2 || w == 3) {
    ad16(&lred[(w - 2) * 4096 + 0 * 32 + colw], acc0, g);
    ad16(&lred[(w - 2) * 4096 + 1 * 32 + colw], acc1, g);
    ad16(&lred[(w - 2) * 4096 + 2 * 32 + colw], acc2, g);
    ad16(&lred[(w - 2) * 4096 + 3 * 32 + colw], acc3, g);
  }
  __syncthreads();
  if (w == 4 || w == 5) {
    ad16(&lred[(w - 4) * 4096 + 0 * 32 + colw], acc0, g);
    ad16(&lred[(w - 4) * 4096 + 1 * 32 + colw], acc1, g);
    ad16(&lred[(w - 4) * 4096 + 2 * 32 + colw], acc2, g);
    ad16(&lred[(w - 4) * 4096 + 3 * 32 + colw], acc3, g);
  }
  __syncthreads();
  if (w == 6 || w == 7) {
    ad16(&lred[(w - 6) * 4096 + 0 * 32 + colw], acc0, g);
    ad16(&lred[(w - 6) * 4096 + 1 * 32 + colw], acc1, g);
    ad16(&lred[(w - 6) * 4096 + 2 * 32 + colw], acc2, g);
    ad16(&lred[(w - 6) * 4096 + 3 * 32 + colw], acc3, g);
  }
  __syncthreads();

  // ---- write fp32 partial: sum the 2 bufs ----
  const int flat = t * 8;  // row = t>>4, col = (t&15)*8
  f32x4 pa = *(f32x4*)&lred[flat];
  f32x4 pb = *(f32x4*)&lred[flat + 4];
  pa += *(f32x4*)&lred[4096 + flat];
  pb += *(f32x4*)&lred[4096 + flat + 4];
  float* pp = part + (size_t)jc * (NN * OUTF) + (size_t)r0 * OUTF + flat;
  *(f32x4*)pp = pa;
  *(f32x4*)(pp + 4) = pb;
}

// ---------------------------------------------------------------------------
// K4: combine 4 partials, divide by denom, elu, store.
// ---------------------------------------------------------------------------
__global__ __launch_bounds__(256) void gat_k4(
    const float* __restrict__ part, const float* __restrict__ dpart,
    float* __restrict__ out) {
  const int idx = blockIdx.x * 256 + threadIdx.x;
  const int e4 = idx * 4;
  const int i = e4 >> 7;
  f32x4 p = {0.f, 0.f, 0.f, 0.f};
  float d = 0.f;
#pragma unroll
  for (int jc = 0; jc < NJC; jc++) {
    p += *(const f32x4*)&part[(size_t)jc * (NN * OUTF) + e4];
    d += dpart[jc * NN + i];
  }
  d = fmaxf(d, 1e-30f);
  f32x4 r;
#pragma unroll
  for (int k = 0; k < 4; k++) {
    float v = p[k] / d;
    r[k] = (v > 0.f) ? v : expm1f(v);
  }
  *(f32x4*)&out[e4] = r;
}

extern "C" void kernel_launch(void* const* d_in, const int* in_sizes, int n_in,
                              void* d_out, int out_size, void* d_ws, size_t ws_size,
                              hipStream_t stream) {
  (void)in_sizes; (void)n_in; (void)out_size; (void)ws_size;
  const float* X  = (const float*)d_in[0];
  const int*  adj = (const int*)d_in[1];
  const float* W  = (const float*)d_in[2];
  const float* a  = (const float*)d_in[3];
  float* out = (float*)d_out;

  char* ws = (char*)d_ws;
  u16*   hbF   = (u16*)ws;                                  // 2 MB @ 0
  float* s1    = (float*)(ws + (2u << 20));                 // 32 KB
  float* s2    = (float*)(ws + (2u << 20) + (32u << 10));   // 32 KB
  float* bmax  = (float*)(ws + (2u << 20) + (64u << 10));   // 32 B
  float* E1    = (float*)(ws + (2u << 20) + (128u << 10));  // 32 KB
  float* E2    = (float*)(ws + (2u << 20) + (160u << 10));  // 32 KB
  float* dpart = (float*)(ws + (2u << 20) + (192u << 10));  // 128 KB
  float* part  = (float*)(ws + (4u << 20));                 // 16 MB @ 4M

  gat_k1<<<NN / 32, 256, 0, stream>>>(X, W, a, hbF, s1, s2);
  gat_k2<<<8, 256, 0, stream>>>(s2, bmax, E1, E2);
  gat_k3<<<256 * NJC, 512, 0, stream>>>(adj, hbF, s1, E1, E2, bmax, part, dpart);
  gat_k4<<<(NN * OUTF / 4) / 256, 256, 0, stream>>>(part, dpart, out);
}